// Round 13
// baseline (446.557 us; speedup 1.0000x reference)
//
#include <hip/hip_runtime.h>
#include <hip/hip_bf16.h>
#include <math.h>

// Problem constants
#define BB 8
#define SS 512
#define VV 32000
#define EE 256
#define NAx 12
#define NCc 24
#define NSt 576
#define MM (BB*SS)   // 4096

typedef __bf16 bf16x8 __attribute__((ext_vector_type(8)));
typedef float f32x4 __attribute__((ext_vector_type(4)));

#define MFMA16(a, b, c) __builtin_amdgcn_mfma_f32_16x16x32_bf16((a), (b), (c), 0, 0, 0)

__device__ __forceinline__ void gl2lds16(const void* g, void* l) {
  __builtin_amdgcn_global_load_lds(
      (const __attribute__((address_space(1))) void*)g,
      (__attribute__((address_space(3))) void*)l, 16, 0, 0);
}

#define FENCE() asm volatile("" ::: "memory")
#define BAR()   do { FENCE(); __builtin_amdgcn_s_barrier(); FENCE(); } while (0)

// ---------------- transpose f32 [R,C] -> bf16 [C,R], 64x64 tiles ----------
__global__ __launch_bounds__(256) void k_transpose64(
    const float* __restrict__ in, __hip_bfloat16* __restrict__ out, int R, int C)
{
  __shared__ float t[64][65];
  const int tx = threadIdx.x, ty = threadIdx.y;   // (64,4)
  const int c0 = blockIdx.x * 64, r0 = blockIdx.y * 64;
#pragma unroll
  for (int i = 0; i < 64; i += 4)
    t[ty + i][tx] = in[(size_t)(r0 + ty + i) * C + (c0 + tx)];
  __syncthreads();
#pragma unroll
  for (int i = 0; i < 64; i += 4)
    out[(size_t)(c0 + ty + i) * R + (r0 + tx)] = __float2bfloat16(t[tx][ty + i]);
}

// ---------------- embed -> axioms -> comps (f32) ----------------
__global__ __launch_bounds__(64) void k_embed_comps(
    const int* __restrict__ ids, const float* __restrict__ ET,
    const float* __restrict__ axw, const float* __restrict__ axb,
    const float* __restrict__ axg, const float* __restrict__ axbeta,
    const float* __restrict__ cw,  const float* __restrict__ cb,
    const float* __restrict__ cg,  const float* __restrict__ cbeta,
    float* __restrict__ comps)
{
  __shared__ float sw[EE * NAx];
  __shared__ float scw[NAx * NCc];
  const int tid = threadIdx.x;
  for (int i = tid; i < EE * NAx; i += 64) sw[i] = axw[i];
  for (int i = tid; i < NAx * NCc; i += 64) scw[i] = cw[i];
  __syncthreads();

  const int m = blockIdx.x * 64 + tid;
  const int id = ids[m];
  const float4* e4 = reinterpret_cast<const float4*>(ET + (size_t)id * EE);

  float a[NAx];
#pragma unroll
  for (int t = 0; t < NAx; ++t) a[t] = axb[t];

  for (int q = 0; q < EE / 4; ++q) {
    float4 v = e4[q];
#pragma unroll
    for (int c = 0; c < 4; ++c) {
      float x = (c == 0) ? v.x : (c == 1) ? v.y : (c == 2) ? v.z : v.w;
      const float* wrow = &sw[(q * 4 + c) * NAx];
#pragma unroll
      for (int t = 0; t < NAx; ++t) a[t] += x * wrow[t];
    }
  }
  {
    float mean = 0.f;
#pragma unroll
    for (int t = 0; t < NAx; ++t) mean += a[t];
    mean *= (1.0f / NAx);
    float var = 0.f;
#pragma unroll
    for (int t = 0; t < NAx; ++t) { float d = a[t] - mean; var += d * d; }
    var *= (1.0f / NAx);
    float rs = rsqrtf(var + 1e-5f);
#pragma unroll
    for (int t = 0; t < NAx; ++t)
      a[t] = tanhf((a[t] - mean) * rs * axg[t] + axbeta[t]);
  }
  float c24[NCc];
#pragma unroll
  for (int j = 0; j < NCc; ++j) c24[j] = cb[j];
#pragma unroll
  for (int t = 0; t < NAx; ++t) {
    float x = a[t];
    const float* wrow = &scw[t * NCc];
#pragma unroll
    for (int j = 0; j < NCc; ++j) c24[j] += x * wrow[j];
  }
  {
    float mean = 0.f;
#pragma unroll
    for (int j = 0; j < NCc; ++j) mean += c24[j];
    mean *= (1.0f / NCc);
    float var = 0.f;
#pragma unroll
    for (int j = 0; j < NCc; ++j) { float d = c24[j] - mean; var += d * d; }
    var *= (1.0f / NCc);
    float rs = rsqrtf(var + 1e-5f);
#pragma unroll
    for (int j = 0; j < NCc; ++j)
      c24[j] = tanhf((c24[j] - mean) * rs * cg[j] + cbeta[j]);
  }
#pragma unroll
  for (int j = 0; j < NCc; ++j) comps[(size_t)m * NCc + j] = c24[j];
}

// ---------------- state recurrence ----------------
__global__ __launch_bounds__(576) void k_recurrence(
    const float* __restrict__ comps, const float* __restrict__ mix,
    __hip_bfloat16* __restrict__ ST, float* __restrict__ fstate)
{
  __shared__ float sc[SS * NCc];
  const int b = blockIdx.x, tid = threadIdx.x;
  const float* src = comps + (size_t)b * SS * NCc;
  for (int i = tid; i < SS * NCc; i += 576) sc[i] = src[i];
  __syncthreads();

  const float sm = 1.0f / (1.0f + expf(-mix[0]));
  const int i = tid / NCc, j = tid - i * NCc;
  float st = 0.0f;
  __hip_bfloat16* stp = ST + (size_t)b * SS * NSt + tid;
  for (int t = 0; t < SS; ++t) {
    float ci = sc[t * NCc + i], cj = sc[t * NCc + j];
    st = 0.9f * st + sm * ci * cj;
    stp[(size_t)t * NSt] = __float2bfloat16(st);
  }
  fstate[b * NSt + tid] = st;
}

// ---------------- 128^2 bf16 GEMM (m97 structure) for GEMM1 ----------------
__global__ __launch_bounds__(256) void k_gemm_bt_gelu(
    const __hip_bfloat16* __restrict__ A,   // [M,K]
    const __hip_bfloat16* __restrict__ Bt,  // [N,K]
    const float* __restrict__ bias,
    __hip_bfloat16* __restrict__ Cb,
    int M, int N, int K)
{
  __shared__ __align__(16) __hip_bfloat16 As[128 * 32];
  __shared__ __align__(16) __hip_bfloat16 Bs[128 * 32];
  const int tid  = threadIdx.x;
  const int lane = tid & 63;
  const int w    = tid >> 6;
  const int wr   = w >> 1, wc = w & 1;
  const int m0 = blockIdx.y * 128;
  const int n0 = blockIdx.x * 128;
  const int lr = lane & 15;
  const int kb = lane >> 4;

  f32x4 acc[4][4];
#pragma unroll
  for (int i = 0; i < 4; ++i)
#pragma unroll
    for (int j = 0; j < 4; ++j) acc[i][j] = (f32x4){0.f, 0.f, 0.f, 0.f};

  for (int k0 = 0; k0 < K; k0 += 32) {
    __syncthreads();
#pragma unroll
    for (int p = 0; p < 2; ++p) {
      const int lbase = w * 2048 + p * 1024;
      const int o  = lbase + lane * 16;
      const int r  = o >> 6;
      const int sg = (o >> 4) & 3;
      gl2lds16(A  + (size_t)(m0 + r) * K + k0 + sg * 8, (char*)As + lbase);
      gl2lds16(Bt + (size_t)(n0 + r) * K + k0 + sg * 8, (char*)Bs + lbase);
    }
    asm volatile("s_waitcnt vmcnt(0)" ::: "memory");
    __syncthreads();

    bf16x8 af[4], bv[4];
#pragma unroll
    for (int mr = 0; mr < 4; ++mr)
      af[mr] = *reinterpret_cast<const bf16x8*>(&As[(wr * 64 + mr * 16 + lr) * 32 + kb * 8]);
#pragma unroll
    for (int nr = 0; nr < 4; ++nr)
      bv[nr] = *reinterpret_cast<const bf16x8*>(&Bs[(wc * 64 + nr * 16 + lr) * 32 + kb * 8]);
#pragma unroll
    for (int mr = 0; mr < 4; ++mr)
#pragma unroll
      for (int nr = 0; nr < 4; ++nr)
        acc[mr][nr] = MFMA16(af[mr], bv[nr], acc[mr][nr]);
  }

#pragma unroll
  for (int nr = 0; nr < 4; ++nr) {
    const int col = n0 + wc * 64 + nr * 16 + lr;
    const float bvs = bias[col];
#pragma unroll
    for (int mr = 0; mr < 4; ++mr) {
      const int rbase = m0 + wr * 64 + mr * 16 + kb * 4;
#pragma unroll
      for (int r = 0; r < 4; ++r) {
        float v = acc[mr][nr][r] + bvs;
        v = 0.5f * v * (1.0f + erff(v * 0.70710678118654752f));
        Cb[(size_t)(rbase + r) * N + col] = __float2bfloat16(v);
      }
    }
  }
}

// ---------------- GEMM2: persistent 128^2, 8 tiles/block, store-in-loop ----
// Same r7 K-loop/swizzles (proven, 273us). New: each block handles 8 tiles
// (mt-fastest, same nt); tile i's output is parked in outv[16] registers and
// NT-stored 2/iter DURING tile i+1's K-loop, pacing DRAM writes under MFMA.
// M=4096, N=32000, K=512 hardcoded. Grid=1000 (%8==0).
__global__ __launch_bounds__(256, 2) void k_gemm2_pers(
    const __hip_bfloat16* __restrict__ A,   // [M,512]
    const __hip_bfloat16* __restrict__ Bt,  // [N,512]
    const float* __restrict__ bias,
    float* __restrict__ C)
{
  __shared__ __align__(16) char smem[65536];  // A: 2x16KB @0, B: 2x16KB @32768

  const int tid = threadIdx.x;
  const int lane = tid & 63;
  const int w  = tid >> 6;          // 0..3
  const int wr = w >> 1;
  const int wc = w & 1;
  const int lr = lane & 15;
  const int kb = lane >> 4;

  // XCD swizzle over 1000 blocks (125/XCD); block handles tiles idx=s*8..s*8+7
  // idx mt-fastest: mt = idx&31, nt = idx>>5 (nt constant within a block).
  const int s = ((int)blockIdx.x & 7) * 125 + ((int)blockIdx.x >> 3);

  const int srow = tid >> 3;
  const int scol = ((tid & 7) ^ (srow & 7)) << 3;
  const int swz0 = (kb ^ (lr & 7)) << 4;
  const int swz1 = swz0 ^ 64;

  // epilogue/store per-thread constants
  const int lrsub = w * 2 + (lane >> 5);          // 0..7
  const int rseg  = (lane & 31) ^ (lrsub & 7);    // LDS read seg (const: p*8%8==0)
  const int c4    = (lane & 31) * 4;

#define STAGE_A(buf, R, tk0)                                              \
  gl2lds16(A + (size_t)(m0 + (R) + srow) * 512 + (tk0) + scol,            \
           smem + (buf)*16384 + (R)*128 + w*1024)
#define STAGE_B(buf, R, tk0)                                              \
  gl2lds16(Bt + (size_t)(n0 + (R) + srow) * 512 + (tk0) + scol,           \
           smem + 32768 + (buf)*16384 + (R)*128 + w*1024)
#define LDA(buf, mf, kh) \
  (*(const bf16x8*)(smem + (buf)*16384 + (wr*64 + (mf)*16 + lr)*128 + ((kh) ? swz1 : swz0)))
#define LDB(buf, nf, kh) \
  (*(const bf16x8*)(smem + 32768 + (buf)*16384 + (wc*64 + (nf)*16 + lr)*128 + ((kh) ? swz1 : swz0)))

// store parked output row p of PREVIOUS tile (pm0/pn0); p is a literal
#define STORE_P(p)                                                            \
  __builtin_nontemporal_store(outv[p],                                        \
      (f32x4*)&C[(size_t)(pm0 + (p)*8 + lrsub) * 32000 + pn0 + c4])

// one K-iteration, T literal 0..7; stores outv[2T] (ph0) and outv[2T+1] (ph3,
// after the boundary wait so vmcnt counts stay load-only-derived).
#define K_ITER(T)                                                             \
  do {                                                                        \
    const int k1 = ((T) + 1) << 6;                                            \
    const int k2 = ((T) + 2) << 6;                                            \
    bf16x8 a0[4], b0[4], a1[4], b1[4];                                        \
    if (hp) STORE_P(2 * (T));                                                 \
    _Pragma("unroll")                                                         \
    for (int mf = 0; mf < 4; ++mf) a0[mf] = LDA((T) & 1, mf, 0);              \
    _Pragma("unroll")                                                         \
    for (int nf = 0; nf < 4; ++nf) b0[nf] = LDB((T) & 1, nf, 0);              \
    if ((T) < 7) { STAGE_A(((T) & 1) ^ 1, 0, k1); STAGE_A(((T) & 1) ^ 1, 32, k1); } \
    BAR();                                                                    \
    asm volatile("s_waitcnt lgkmcnt(0)" ::: "memory");                        \
    __builtin_amdgcn_sched_barrier(0);                                        \
    __builtin_amdgcn_s_setprio(1);                                            \
    _Pragma("unroll")                                                         \
    for (int mf = 0; mf < 4; ++mf) {                                          \
      acc[mf][0] = MFMA16(a0[mf], b0[0], acc[mf][0]);                         \
      acc[mf][1] = MFMA16(a0[mf], b0[1], acc[mf][1]);                         \
    }                                                                         \
    __builtin_amdgcn_s_setprio(0);                                            \
    BAR();                                                                    \
    _Pragma("unroll")                                                         \
    for (int mf = 0; mf < 4; ++mf) a1[mf] = LDA((T) & 1, mf, 1);              \
    _Pragma("unroll")                                                         \
    for (int nf = 0; nf < 4; ++nf) b1[nf] = LDB((T) & 1, nf, 1);              \
    if ((T) < 7) { STAGE_A(((T) & 1) ^ 1, 64, k1); STAGE_A(((T) & 1) ^ 1, 96, k1); } \
    BAR();                                                                    \
    asm volatile("s_waitcnt lgkmcnt(0)" ::: "memory");                        \
    __builtin_amdgcn_sched_barrier(0);                                        \
    __builtin_amdgcn_s_setprio(1);                                            \
    _Pragma("unroll")                                                         \
    for (int mf = 0; mf < 4; ++mf) {                                          \
      acc[mf][2] = MFMA16(a0[mf], b0[2], acc[mf][2]);                         \
      acc[mf][3] = MFMA16(a0[mf], b0[3], acc[mf][3]);                         \
    }                                                                         \
    __builtin_amdgcn_s_setprio(0);                                            \
    BAR();                                                                    \
    if ((T) < 6) { STAGE_B((T) & 1, 0, k2); STAGE_B((T) & 1, 32, k2); }       \
    BAR();                                                                    \
    __builtin_amdgcn_s_setprio(1);                                            \
    _Pragma("unroll")                                                         \
    for (int mf = 0; mf < 4; ++mf) {                                          \
      acc[mf][0] = MFMA16(a1[mf], b1[0], acc[mf][0]);                         \
      acc[mf][1] = MFMA16(a1[mf], b1[1], acc[mf][1]);                         \
    }                                                                         \
    __builtin_amdgcn_s_setprio(0);                                            \
    BAR();                                                                    \
    if ((T) < 6) { STAGE_B((T) & 1, 64, k2); STAGE_B((T) & 1, 96, k2); }      \
    BAR();                                                                    \
    __builtin_amdgcn_s_setprio(1);                                            \
    _Pragma("unroll")                                                         \
    for (int mf = 0; mf < 4; ++mf) {                                          \
      acc[mf][2] = MFMA16(a1[mf], b1[2], acc[mf][2]);                         \
      acc[mf][3] = MFMA16(a1[mf], b1[3], acc[mf][3]);                         \
    }                                                                         \
    __builtin_amdgcn_s_setprio(0);                                            \
    if ((T) < 6) {                                                            \
      asm volatile("s_waitcnt vmcnt(4)" ::: "memory");                        \
    } else if ((T) == 6) {                                                    \
      asm volatile("s_waitcnt vmcnt(0)" ::: "memory");                        \
    }                                                                         \
    if (hp) STORE_P(2 * (T) + 1);                                             \
    BAR();                                                                    \
  } while (0)

  f32x4 outv[16];
#pragma unroll
  for (int p = 0; p < 16; ++p) outv[p] = (f32x4){0.f, 0.f, 0.f, 0.f};
  int pm0 = 0, pn0 = 0;

#pragma unroll 1
  for (int ti = 0; ti < 8; ++ti) {
    const int idx = s * 8 + ti;
    const int mt  = idx & 31;
    const int nt  = idx >> 5;
    const int m0  = mt << 7;
    const int n0  = nt << 7;
    const bool hp = (ti != 0);

    float bvs[4];
#pragma unroll
    for (int nf = 0; nf < 4; ++nf) bvs[nf] = bias[n0 + wc * 64 + nf * 16 + lr];

    f32x4 acc[4][4];
#pragma unroll
    for (int i = 0; i < 4; ++i)
#pragma unroll
      for (int j = 0; j < 4; ++j) acc[i][j] = (f32x4){0.f, 0.f, 0.f, 0.f};

    // prologue: A(0), B(0), B(1); wait first 8 of 12
    STAGE_A(0, 0, 0);  STAGE_A(0, 32, 0);  STAGE_A(0, 64, 0);  STAGE_A(0, 96, 0);
    STAGE_B(0, 0, 0);  STAGE_B(0, 32, 0);  STAGE_B(0, 64, 0);  STAGE_B(0, 96, 0);
    STAGE_B(1, 0, 64); STAGE_B(1, 32, 64); STAGE_B(1, 64, 64); STAGE_B(1, 96, 64);
    asm volatile("s_waitcnt vmcnt(4)" ::: "memory");
    BAR();

    K_ITER(0); K_ITER(1); K_ITER(2); K_ITER(3);
    K_ITER(4); K_ITER(5); K_ITER(6); K_ITER(7);

    // tile epilogue: acc(+bias) -> LDS (swizzled) -> outv registers
    {
      float* ls = (float*)smem;
#pragma unroll
      for (int mf = 0; mf < 4; ++mf) {
#pragma unroll
        for (int nf = 0; nf < 4; ++nf) {
          const int col = wc * 64 + nf * 16 + lr;
#pragma unroll
          for (int r = 0; r < 4; ++r) {
            const int row = wr * 64 + mf * 16 + kb * 4 + r;
            const int seg = (col >> 2) ^ (row & 7);
            ls[row * 128 + seg * 4 + (col & 3)] = acc[mf][nf][r] + bvs[nf];
          }
        }
      }
      asm volatile("s_waitcnt lgkmcnt(0)" ::: "memory");
      BAR();
#pragma unroll
      for (int p = 0; p < 16; ++p)
        outv[p] = *(const f32x4*)&ls[(p * 8 + lrsub) * 128 + rseg * 4];
      asm volatile("s_waitcnt lgkmcnt(0)" ::: "memory");
      BAR();   // LDS free for next tile's prologue
    }
    pm0 = m0; pn0 = n0;
  }

  // drain: store the last tile's parked output
#pragma unroll
  for (int p = 0; p < 16; ++p) STORE_P(p);

#undef STAGE_A
#undef STAGE_B
#undef LDA
#undef LDB
#undef STORE_P
#undef K_ITER
}

// ---------------- launch ----------------
extern "C" void kernel_launch(void* const* d_in, const int* in_sizes, int n_in,
                              void* d_out, int out_size, void* d_ws, size_t ws_size,
                              hipStream_t stream) {
  const int*   ids  = (const int*)  d_in[0];
  const float* ET   = (const float*)d_in[1];
  const float* axw  = (const float*)d_in[2];
  const float* axb  = (const float*)d_in[3];
  const float* axg  = (const float*)d_in[4];
  const float* axbt = (const float*)d_in[5];
  const float* cw   = (const float*)d_in[6];
  const float* cb   = (const float*)d_in[7];
  const float* cg   = (const float*)d_in[8];
  const float* cbt  = (const float*)d_in[9];
  const float* mix  = (const float*)d_in[10];
  const float* w1   = (const float*)d_in[11];
  const float* b1   = (const float*)d_in[12];
  const float* w2   = (const float*)d_in[13];
  const float* b2   = (const float*)d_in[14];

  float* out = (float*)d_out;

  char* ws = (char*)d_ws;
  size_t o = 0;
  __hip_bfloat16* W2T   = (__hip_bfloat16*)(ws + o); o += (size_t)VV * 512 * 2;
  __hip_bfloat16* W1T   = (__hip_bfloat16*)(ws + o); o += (size_t)512 * NSt * 2;
  float*          comps = (float*)(ws + o);          o += (size_t)MM * NCc * 4;
  __hip_bfloat16* STb   = (__hip_bfloat16*)(ws + o); o += (size_t)MM * NSt * 2;
  __hip_bfloat16* H     = (__hip_bfloat16*)(ws + o); o += (size_t)MM * 512 * 2;

  // W2 [512,32000] -> W2T bf16 [32000,512]; W1 [576,512] -> W1T bf16 [512,576]
  k_transpose64<<<dim3(VV / 64, 512 / 64), dim3(64, 4), 0, stream>>>(w2, W2T, 512, VV);
  k_transpose64<<<dim3(512 / 64, NSt / 64), dim3(64, 4), 0, stream>>>(w1, W1T, NSt, 512);

  k_embed_comps<<<MM / 64, 64, 0, stream>>>(ids, ET, axw, axb, axg, axbt,
                                            cw, cb, cg, cbt, comps);

  k_recurrence<<<BB, NSt, 0, stream>>>(comps, mix, STb, out + (size_t)MM * VV);

  // GEMM1: H = gelu(ST @ W1 + b1)  (M=4096, N=512, K=576)
  k_gemm_bt_gelu<<<dim3(512 / 128, MM / 128), 256, 0, stream>>>(
      STb, W1T, b1, H, MM, 512, NSt);

  // GEMM2: logits = H @ W2 + b2  — persistent, 1000 blocks x 8 tiles
  k_gemm2_pers<<<1000, 256, 0, stream>>>(H, W2T, b2, out);
}

// Round 14
// 276.761 us; speedup vs baseline: 1.6135x; 1.6135x over previous
//
#include <hip/hip_runtime.h>
#include <hip/hip_bf16.h>
#include <math.h>

// Problem constants
#define BB 8
#define SS 512
#define VV 32000
#define EE 256
#define NAx 12
#define NCc 24
#define NSt 576
#define MM (BB*SS)   // 4096

typedef __bf16 bf16x8 __attribute__((ext_vector_type(8)));
typedef float f32x4 __attribute__((ext_vector_type(4)));

#define MFMA16(a, b, c) __builtin_amdgcn_mfma_f32_16x16x32_bf16((a), (b), (c), 0, 0, 0)

__device__ __forceinline__ void gl2lds16(const void* g, void* l) {
  __builtin_amdgcn_global_load_lds(
      (const __attribute__((address_space(1))) void*)g,
      (__attribute__((address_space(3))) void*)l, 16, 0, 0);
}

#define FENCE() asm volatile("" ::: "memory")
#define BAR()   do { FENCE(); __builtin_amdgcn_s_barrier(); FENCE(); } while (0)

// ---------------- W2 transpose f32 [512][32000] -> bf16 [32000][512] -------
// Wide version: float4 reads (16B/lane), ushort4 writes (8B/lane = 512B/wave).
__global__ __launch_bounds__(256) void k_transpose_w2(
    const float* __restrict__ in, __hip_bfloat16* __restrict__ out)
{
  __shared__ __hip_bfloat16 tb[64][260];   // pad 260: 8B-aligned rows, <=2-way banks
  const int tid = threadIdx.x;
  const int c0 = blockIdx.x * 64;          // column tile (N dim, 500 blocks)
  const int r0 = blockIdx.y * 256;         // row tile (K dim, 2 blocks)
  const int rr = tid >> 4;                 // 0..15
  const int cc = (tid & 15) * 4;
#pragma unroll
  for (int p = 0; p < 16; ++p) {
    const int r = p * 16 + rr;
    float4 v = *(const float4*)&in[(size_t)(r0 + r) * 32000 + c0 + cc];
    tb[cc + 0][r] = __float2bfloat16(v.x);
    tb[cc + 1][r] = __float2bfloat16(v.y);
    tb[cc + 2][r] = __float2bfloat16(v.z);
    tb[cc + 3][r] = __float2bfloat16(v.w);
  }
  __syncthreads();
  const int w = tid >> 6, lane = tid & 63;
#pragma unroll
  for (int q = 0; q < 16; ++q) {
    const int c = q * 4 + w;
    ushort4 u = *(const ushort4*)&tb[c][lane * 4];
    *(ushort4*)&out[(size_t)(c0 + c) * 512 + r0 + lane * 4] = u;
  }
}

// ---------------- transpose f32 [R,C] -> bf16 [C,R], 64x64 tiles (W1) ------
__global__ __launch_bounds__(256) void k_transpose64(
    const float* __restrict__ in, __hip_bfloat16* __restrict__ out, int R, int C)
{
  __shared__ float t[64][65];
  const int tx = threadIdx.x, ty = threadIdx.y;   // (64,4)
  const int c0 = blockIdx.x * 64, r0 = blockIdx.y * 64;
#pragma unroll
  for (int i = 0; i < 64; i += 4)
    t[ty + i][tx] = in[(size_t)(r0 + ty + i) * C + (c0 + tx)];
  __syncthreads();
#pragma unroll
  for (int i = 0; i < 64; i += 4)
    out[(size_t)(c0 + ty + i) * R + (r0 + tx)] = __float2bfloat16(t[tx][ty + i]);
}

// ---------------- embed -> axioms -> comps (f32) ----------------
__global__ __launch_bounds__(64) void k_embed_comps(
    const int* __restrict__ ids, const float* __restrict__ ET,
    const float* __restrict__ axw, const float* __restrict__ axb,
    const float* __restrict__ axg, const float* __restrict__ axbeta,
    const float* __restrict__ cw,  const float* __restrict__ cb,
    const float* __restrict__ cg,  const float* __restrict__ cbeta,
    float* __restrict__ comps)
{
  __shared__ float sw[EE * NAx];
  __shared__ float scw[NAx * NCc];
  const int tid = threadIdx.x;
  for (int i = tid; i < EE * NAx; i += 64) sw[i] = axw[i];
  for (int i = tid; i < NAx * NCc; i += 64) scw[i] = cw[i];
  __syncthreads();

  const int m = blockIdx.x * 64 + tid;
  const int id = ids[m];
  const float4* e4 = reinterpret_cast<const float4*>(ET + (size_t)id * EE);

  float a[NAx];
#pragma unroll
  for (int t = 0; t < NAx; ++t) a[t] = axb[t];

  for (int q = 0; q < EE / 4; ++q) {
    float4 v = e4[q];
#pragma unroll
    for (int c = 0; c < 4; ++c) {
      float x = (c == 0) ? v.x : (c == 1) ? v.y : (c == 2) ? v.z : v.w;
      const float* wrow = &sw[(q * 4 + c) * NAx];
#pragma unroll
      for (int t = 0; t < NAx; ++t) a[t] += x * wrow[t];
    }
  }
  {
    float mean = 0.f;
#pragma unroll
    for (int t = 0; t < NAx; ++t) mean += a[t];
    mean *= (1.0f / NAx);
    float var = 0.f;
#pragma unroll
    for (int t = 0; t < NAx; ++t) { float d = a[t] - mean; var += d * d; }
    var *= (1.0f / NAx);
    float rs = rsqrtf(var + 1e-5f);
#pragma unroll
    for (int t = 0; t < NAx; ++t)
      a[t] = tanhf((a[t] - mean) * rs * axg[t] + axbeta[t]);
  }
  float c24[NCc];
#pragma unroll
  for (int j = 0; j < NCc; ++j) c24[j] = cb[j];
#pragma unroll
  for (int t = 0; t < NAx; ++t) {
    float x = a[t];
    const float* wrow = &scw[t * NCc];
#pragma unroll
    for (int j = 0; j < NCc; ++j) c24[j] += x * wrow[j];
  }
  {
    float mean = 0.f;
#pragma unroll
    for (int j = 0; j < NCc; ++j) mean += c24[j];
    mean *= (1.0f / NCc);
    float var = 0.f;
#pragma unroll
    for (int j = 0; j < NCc; ++j) { float d = c24[j] - mean; var += d * d; }
    var *= (1.0f / NCc);
    float rs = rsqrtf(var + 1e-5f);
#pragma unroll
    for (int j = 0; j < NCc; ++j)
      c24[j] = tanhf((c24[j] - mean) * rs * cg[j] + cbeta[j]);
  }
#pragma unroll
  for (int j = 0; j < NCc; ++j) comps[(size_t)m * NCc + j] = c24[j];
}

// ---------------- state recurrence (distance-1 LDS prefetch) ----------------
__global__ __launch_bounds__(576) void k_recurrence(
    const float* __restrict__ comps, const float* __restrict__ mix,
    __hip_bfloat16* __restrict__ ST, float* __restrict__ fstate)
{
  __shared__ float sc[SS * NCc];
  const int b = blockIdx.x, tid = threadIdx.x;
  const float* src = comps + (size_t)b * SS * NCc;
  for (int i = tid; i < SS * NCc; i += 576) sc[i] = src[i];
  __syncthreads();

  const float sm = 1.0f / (1.0f + expf(-mix[0]));
  const int i = tid / NCc, j = tid - i * NCc;
  float st = 0.0f;
  __hip_bfloat16* stp = ST + (size_t)b * SS * NSt + tid;
  float ci = sc[i], cj = sc[j];
#pragma unroll 4
  for (int t = 0; t < SS; ++t) {
    const int tn = t + 1;
    float nci = (tn < SS) ? sc[tn * NCc + i] : 0.f;   // prefetch overlaps FMA+store
    float ncj = (tn < SS) ? sc[tn * NCc + j] : 0.f;
    st = 0.9f * st + sm * ci * cj;
    stp[(size_t)t * NSt] = __float2bfloat16(st);
    ci = nci; cj = ncj;
  }
  fstate[b * NSt + tid] = st;
}

// ---------------- 128^2 bf16 GEMM (m97 structure) for GEMM1 ----------------
__global__ __launch_bounds__(256) void k_gemm_bt_gelu(
    const __hip_bfloat16* __restrict__ A,   // [M,K]
    const __hip_bfloat16* __restrict__ Bt,  // [N,K]
    const float* __restrict__ bias,
    __hip_bfloat16* __restrict__ Cb,
    int M, int N, int K)
{
  __shared__ __align__(16) __hip_bfloat16 As[128 * 32];
  __shared__ __align__(16) __hip_bfloat16 Bs[128 * 32];
  const int tid  = threadIdx.x;
  const int lane = tid & 63;
  const int w    = tid >> 6;
  const int wr   = w >> 1, wc = w & 1;
  const int m0 = blockIdx.y * 128;
  const int n0 = blockIdx.x * 128;
  const int lr = lane & 15;
  const int kb = lane >> 4;

  f32x4 acc[4][4];
#pragma unroll
  for (int i = 0; i < 4; ++i)
#pragma unroll
    for (int j = 0; j < 4; ++j) acc[i][j] = (f32x4){0.f, 0.f, 0.f, 0.f};

  for (int k0 = 0; k0 < K; k0 += 32) {
    __syncthreads();
#pragma unroll
    for (int p = 0; p < 2; ++p) {
      const int lbase = w * 2048 + p * 1024;
      const int o  = lbase + lane * 16;
      const int r  = o >> 6;
      const int sg = (o >> 4) & 3;
      gl2lds16(A  + (size_t)(m0 + r) * K + k0 + sg * 8, (char*)As + lbase);
      gl2lds16(Bt + (size_t)(n0 + r) * K + k0 + sg * 8, (char*)Bs + lbase);
    }
    asm volatile("s_waitcnt vmcnt(0)" ::: "memory");
    __syncthreads();

    bf16x8 af[4], bv[4];
#pragma unroll
    for (int mr = 0; mr < 4; ++mr)
      af[mr] = *reinterpret_cast<const bf16x8*>(&As[(wr * 64 + mr * 16 + lr) * 32 + kb * 8]);
#pragma unroll
    for (int nr = 0; nr < 4; ++nr)
      bv[nr] = *reinterpret_cast<const bf16x8*>(&Bs[(wc * 64 + nr * 16 + lr) * 32 + kb * 8]);
#pragma unroll
    for (int mr = 0; mr < 4; ++mr)
#pragma unroll
      for (int nr = 0; nr < 4; ++nr)
        acc[mr][nr] = MFMA16(af[mr], bv[nr], acc[mr][nr]);
  }

#pragma unroll
  for (int nr = 0; nr < 4; ++nr) {
    const int col = n0 + wc * 64 + nr * 16 + lr;
    const float bvs = bias[col];
#pragma unroll
    for (int mr = 0; mr < 4; ++mr) {
      const int rbase = m0 + wr * 64 + mr * 16 + kb * 4;
#pragma unroll
      for (int r = 0; r < 4; ++r) {
        float v = acc[mr][nr][r] + bvs;
        v = 0.5f * v * (1.0f + erff(v * 0.70710678118654752f));
        Cb[(size_t)(rbase + r) * N + col] = __float2bfloat16(v);
      }
    }
  }
}

// ---------------- GEMM2: 128^2 tile, BK=64, 4 waves, 2 blocks/CU ----------
// EXACT round-7 structure (best known: 273us total): counted-vmcnt 4-phase
// K-loop, mt-fastest XCD swizzle, LDS-coalesced epilogue, NT f32x4 stores.
// Requires: M%128==0, N%128==0, K%64==0, K/64>=2, grid%8==0.
__global__ __launch_bounds__(256, 2) void k_gemm2_128(
    const __hip_bfloat16* __restrict__ A,   // [M,K]
    const __hip_bfloat16* __restrict__ Bt,  // [N,K]
    const float* __restrict__ bias,
    float* __restrict__ C,
    int M, int N, int K, int tiles_m)
{
  __shared__ __align__(16) char smem[65536];  // A: 2x16KB @0, B: 2x16KB @32768

  const int NK  = K >> 6;
  const int tid = threadIdx.x;
  const int lane = tid & 63;
  const int w  = tid >> 6;          // 0..3
  const int wr = w >> 1;            // M half
  const int wc = w & 1;             // N half
  const int lr = lane & 15;
  const int kb = lane >> 4;

  // T1: bijective XCD swizzle (grid % 8 == 0); mt fastest -> B panel L2-reuse
  const int nwg = gridDim.x;
  const int cpx = nwg >> 3;
  const int s   = ((int)blockIdx.x & 7) * cpx + ((int)blockIdx.x >> 3);
  const int nt  = s / tiles_m;
  const int mt  = s - nt * tiles_m;
  const int m0  = mt << 7;
  const int n0  = nt << 7;

  // stage-side (linear LDS dest, inverse-swizzled global source)
  const int srow = tid >> 3;                       // 0..31
  const int scol = ((tid & 7) ^ (srow & 7)) << 3;  // element offset in K-tile
  // read-side swizzle
  const int swz0 = (kb ^ (lr & 7)) << 4;
  const int swz1 = swz0 ^ 64;

  // one call stages a 32-row chunk (R in {0,32,64,96}) of a 128x64 bf16 tile
#define STAGE_A(buf, R, tk0)                                              \
  gl2lds16(A + (size_t)(m0 + (R) + srow) * K + (tk0) + scol,              \
           smem + (buf)*16384 + (R)*128 + w*1024)
#define STAGE_B(buf, R, tk0)                                              \
  gl2lds16(Bt + (size_t)(n0 + (R) + srow) * K + (tk0) + scol,             \
           smem + 32768 + (buf)*16384 + (R)*128 + w*1024)

#define LDA(buf, mf, kh) \
  (*(const bf16x8*)(smem + (buf)*16384 + (wr*64 + (mf)*16 + lr)*128 + ((kh) ? swz1 : swz0)))
#define LDB(buf, nf, kh) \
  (*(const bf16x8*)(smem + 32768 + (buf)*16384 + (wc*64 + (nf)*16 + lr)*128 + ((kh) ? swz1 : swz0)))

  f32x4 acc[4][4];
#pragma unroll
  for (int i = 0; i < 4; ++i)
#pragma unroll
    for (int j = 0; j < 4; ++j) acc[i][j] = (f32x4){0.f, 0.f, 0.f, 0.f};

  float bvs[4];
#pragma unroll
  for (int nf = 0; nf < 4; ++nf) bvs[nf] = bias[n0 + wc * 64 + nf * 16 + lr];

  // ---- prologue: A(0), B(0), B(1)  (12 loads/thread, wait oldest 8)
  STAGE_A(0, 0, 0);  STAGE_A(0, 32, 0);  STAGE_A(0, 64, 0);  STAGE_A(0, 96, 0);
  STAGE_B(0, 0, 0);  STAGE_B(0, 32, 0);  STAGE_B(0, 64, 0);  STAGE_B(0, 96, 0);
  STAGE_B(1, 0, 64); STAGE_B(1, 32, 64); STAGE_B(1, 64, 64); STAGE_B(1, 96, 64);
  asm volatile("s_waitcnt vmcnt(4)" ::: "memory");   // tile0 (A+B) landed
  BAR();

#pragma unroll 1
  for (int t = 0; t < NK; ++t) {
    const int c  = t & 1;
    const int k1 = (t + 1) << 6;
    const int k2 = (t + 2) << 6;
    bf16x8 a0[4], b0[4], a1[4], b1[4];

    // phase 0: read kh0 frags; stage A(t+1) half; MFMA kh0 x nf0,1
#pragma unroll
    for (int mf = 0; mf < 4; ++mf) a0[mf] = LDA(c, mf, 0);
#pragma unroll
    for (int nf = 0; nf < 4; ++nf) b0[nf] = LDB(c, nf, 0);
    if (t < NK - 1) { STAGE_A(c ^ 1, 0, k1); STAGE_A(c ^ 1, 32, k1); }
    BAR();
    asm volatile("s_waitcnt lgkmcnt(0)" ::: "memory");
    __builtin_amdgcn_sched_barrier(0);
    __builtin_amdgcn_s_setprio(1);
#pragma unroll
    for (int mf = 0; mf < 4; ++mf) {
      acc[mf][0] = MFMA16(a0[mf], b0[0], acc[mf][0]);
      acc[mf][1] = MFMA16(a0[mf], b0[1], acc[mf][1]);
    }
    __builtin_amdgcn_s_setprio(0);
    BAR();

    // phase 1: read kh1 frags; stage A(t+1) half; MFMA kh0 x nf2,3
#pragma unroll
    for (int mf = 0; mf < 4; ++mf) a1[mf] = LDA(c, mf, 1);
#pragma unroll
    for (int nf = 0; nf < 4; ++nf) b1[nf] = LDB(c, nf, 1);
    if (t < NK - 1) { STAGE_A(c ^ 1, 64, k1); STAGE_A(c ^ 1, 96, k1); }
    BAR();
    asm volatile("s_waitcnt lgkmcnt(0)" ::: "memory");   // buf c fully consumed
    __builtin_amdgcn_sched_barrier(0);
    __builtin_amdgcn_s_setprio(1);
#pragma unroll
    for (int mf = 0; mf < 4; ++mf) {
      acc[mf][2] = MFMA16(a0[mf], b0[2], acc[mf][2]);
      acc[mf][3] = MFMA16(a0[mf], b0[3], acc[mf][3]);
    }
    __builtin_amdgcn_s_setprio(0);
    BAR();

    // phase 2: stage B(t+2) into just-freed buf c; MFMA kh1 x nf0,1
    if (t < NK - 2) { STAGE_B(c, 0, k2); STAGE_B(c, 32, k2); }
    BAR();
    __builtin_amdgcn_s_setprio(1);
#pragma unroll
    for (int mf = 0; mf < 4; ++mf) {
      acc[mf][0] = MFMA16(a1[mf], b1[0], acc[mf][0]);
      acc[mf][1] = MFMA16(a1[mf], b1[1], acc[mf][1]);
    }
    __builtin_amdgcn_s_setprio(0);
    BAR();

    // phase 3: stage B(t+2); MFMA kh1 x nf2,3; boundary wait
    if (t < NK - 2) { STAGE_B(c, 64, k2); STAGE_B(c, 96, k2); }
    BAR();
    __builtin_amdgcn_s_setprio(1);
#pragma unroll
    for (int mf = 0; mf < 4; ++mf) {
      acc[mf][2] = MFMA16(a1[mf], b1[2], acc[mf][2]);
      acc[mf][3] = MFMA16(a1[mf], b1[3], acc[mf][3]);
    }
    __builtin_amdgcn_s_setprio(0);
    if (t < NK - 2) {
      asm volatile("s_waitcnt vmcnt(4)" ::: "memory");   // tile t+1 landed
    } else if (t == NK - 2) {
      asm volatile("s_waitcnt vmcnt(0)" ::: "memory");
    }
    BAR();
  }

  // ---- epilogue: one LDS phase (128x128 f32 = 64 KB), 512B-contig NT stores
  float* ls = (float*)smem;
#pragma unroll
  for (int mf = 0; mf < 4; ++mf) {
#pragma unroll
    for (int nf = 0; nf < 4; ++nf) {
      const int col = wc * 64 + nf * 16 + lr;
#pragma unroll
      for (int r = 0; r < 4; ++r) {
        const int row = wr * 64 + mf * 16 + kb * 4 + r;
        const int seg = (col >> 2) ^ (row & 7);
        ls[row * 128 + seg * 4 + (col & 3)] = acc[mf][nf][r] + bvs[nf];
      }
    }
  }
  asm volatile("s_waitcnt lgkmcnt(0)" ::: "memory");
  BAR();
#pragma unroll
  for (int pass = 0; pass < 16; ++pass) {
    const int lrow = pass * 8 + w * 2 + (lane >> 5);
    const int seg  = (lane & 31) ^ (lrow & 7);
    f32x4 v = *(const f32x4*)&ls[lrow * 128 + seg * 4];
    __builtin_nontemporal_store(v,
        (f32x4*)&C[(size_t)(m0 + lrow) * N + n0 + (lane & 31) * 4]);
  }
#undef STAGE_A
#undef STAGE_B
#undef LDA
#undef LDB
}

// ---------------- launch ----------------
extern "C" void kernel_launch(void* const* d_in, const int* in_sizes, int n_in,
                              void* d_out, int out_size, void* d_ws, size_t ws_size,
                              hipStream_t stream) {
  const int*   ids  = (const int*)  d_in[0];
  const float* ET   = (const float*)d_in[1];
  const float* axw  = (const float*)d_in[2];
  const float* axb  = (const float*)d_in[3];
  const float* axg  = (const float*)d_in[4];
  const float* axbt = (const float*)d_in[5];
  const float* cw   = (const float*)d_in[6];
  const float* cb   = (const float*)d_in[7];
  const float* cg   = (const float*)d_in[8];
  const float* cbt  = (const float*)d_in[9];
  const float* mix  = (const float*)d_in[10];
  const float* w1   = (const float*)d_in[11];
  const float* b1   = (const float*)d_in[12];
  const float* w2   = (const float*)d_in[13];
  const float* b2   = (const float*)d_in[14];

  float* out = (float*)d_out;

  char* ws = (char*)d_ws;
  size_t o = 0;
  __hip_bfloat16* W2T   = (__hip_bfloat16*)(ws + o); o += (size_t)VV * 512 * 2;
  __hip_bfloat16* W1T   = (__hip_bfloat16*)(ws + o); o += (size_t)512 * NSt * 2;
  float*          comps = (float*)(ws + o);          o += (size_t)MM * NCc * 4;
  __hip_bfloat16* STb   = (__hip_bfloat16*)(ws + o); o += (size_t)MM * NSt * 2;
  __hip_bfloat16* H     = (__hip_bfloat16*)(ws + o); o += (size_t)MM * 512 * 2;

  // W2 [512,32000] -> W2T bf16 [32000,512] (wide); W1 -> W1T [512,576]
  k_transpose_w2<<<dim3(VV / 64, 2), 256, 0, stream>>>(w2, W2T);
  k_transpose64<<<dim3(512 / 64, NSt / 64), dim3(64, 4), 0, stream>>>(w1, W1T, NSt, 512);

  k_embed_comps<<<MM / 64, 64, 0, stream>>>(ids, ET, axw, axb, axg, axbt,
                                            cw, cb, cg, cbt, comps);

  k_recurrence<<<BB, NSt, 0, stream>>>(comps, mix, STb, out + (size_t)MM * VV);

  // GEMM1: H = gelu(ST @ W1 + b1)  (M=4096, N=512, K=576)
  k_gemm_bt_gelu<<<dim3(512 / 128, MM / 128), 256, 0, stream>>>(
      STb, W1T, b1, H, MM, 512, NSt);

  // GEMM2: logits = H @ W2 + b2  (M=4096, N=32000, K=512), r7 config
  k_gemm2_128<<<(VV / 128) * (MM / 128), 256, 0, stream>>>(
      H, W2T, b2, out, MM, VV, 512, MM / 128);
}

// Round 15
// 263.801 us; speedup vs baseline: 1.6928x; 1.0491x over previous
//
#include <hip/hip_runtime.h>
#include <hip/hip_bf16.h>
#include <math.h>

// Problem constants
#define BB 8
#define SS 512
#define VV 32000
#define EE 256
#define NAx 12
#define NCc 24
#define NSt 576
#define MM (BB*SS)   // 4096

typedef __bf16 bf16x8 __attribute__((ext_vector_type(8)));
typedef float f32x4 __attribute__((ext_vector_type(4)));

#define MFMA16(a, b, c) __builtin_amdgcn_mfma_f32_16x16x32_bf16((a), (b), (c), 0, 0, 0)

__device__ __forceinline__ void gl2lds16(const void* g, void* l) {
  __builtin_amdgcn_global_load_lds(
      (const __attribute__((address_space(1))) void*)g,
      (__attribute__((address_space(3))) void*)l, 16, 0, 0);
}

#define FENCE() asm volatile("" ::: "memory")
#define BAR()   do { FENCE(); __builtin_amdgcn_s_barrier(); FENCE(); } while (0)

// ---------------- fused prep: W2 transpose | W1 transpose | embed ----------
// blocks [0,1000): W2 [512][32000] -> bf16 [32000][512] (64-col x 256-row tiles)
// blocks [1000,1072): W1 [576][512] -> bf16 [512][576]  (64x64 tiles)
// blocks [1072,1088): embed->axioms->comps, 256 positions/block
__global__ __launch_bounds__(256) void k_prep(
    const float* __restrict__ w2, __hip_bfloat16* __restrict__ W2T,
    const float* __restrict__ w1, __hip_bfloat16* __restrict__ W1T,
    const int* __restrict__ ids, const float* __restrict__ ET,
    const float* __restrict__ axw, const float* __restrict__ axb,
    const float* __restrict__ axg, const float* __restrict__ axbeta,
    const float* __restrict__ cw,  const float* __restrict__ cb,
    const float* __restrict__ cg,  const float* __restrict__ cbeta,
    float* __restrict__ comps)
{
  __shared__ __align__(16) char smu[33280];   // union: max of the 3 paths
  const int bid = blockIdx.x, tid = threadIdx.x;

  if (bid < 1000) {
    // ---- W2 transpose: float4 reads, ushort4 writes (512B/wave-instr)
    __hip_bfloat16 (*tb)[260] = (__hip_bfloat16 (*)[260])smu;  // [64 cols][260]
    const int c0 = (bid % 500) * 64;
    const int r0 = (bid / 500) * 256;
    const int rr = tid >> 4;                 // 0..15
    const int cc = (tid & 15) * 4;
#pragma unroll
    for (int p = 0; p < 16; ++p) {
      const int r = p * 16 + rr;
      float4 v = *(const float4*)&w2[(size_t)(r0 + r) * 32000 + c0 + cc];
      tb[cc + 0][r] = __float2bfloat16(v.x);
      tb[cc + 1][r] = __float2bfloat16(v.y);
      tb[cc + 2][r] = __float2bfloat16(v.z);
      tb[cc + 3][r] = __float2bfloat16(v.w);
    }
    __syncthreads();
    const int w = tid >> 6, lane = tid & 63;
#pragma unroll
    for (int q = 0; q < 16; ++q) {
      const int c = q * 4 + w;
      ushort4 u = *(const ushort4*)&tb[c][lane * 4];
      *(ushort4*)&W2T[(size_t)(c0 + c) * 512 + r0 + lane * 4] = u;
    }
  } else if (bid < 1072) {
    // ---- W1 transpose 64x64
    float (*t)[65] = (float (*)[65])smu;
    const int idx = bid - 1000;
    const int bx = idx & 7;          // over C=512
    const int by = idx >> 3;         // over R=576
    const int tx = tid & 63, ty = tid >> 6;
    const int c0 = bx * 64, r0 = by * 64;
#pragma unroll
    for (int i = 0; i < 64; i += 4)
      t[ty + i][tx] = w1[(size_t)(r0 + ty + i) * 512 + c0 + tx];
    __syncthreads();
#pragma unroll
    for (int i = 0; i < 64; i += 4)
      W1T[(size_t)(c0 + ty + i) * 576 + r0 + tx] = __float2bfloat16(t[tx][ty + i]);
  } else {
    // ---- embed -> axioms -> comps
    float* sw  = (float*)smu;            // [256*12]
    float* scw = sw + EE * NAx;          // [12*24]
    for (int i = tid; i < EE * NAx; i += 256) sw[i] = axw[i];
    for (int i = tid; i < NAx * NCc; i += 256) scw[i] = cw[i];
    __syncthreads();

    const int m = (bid - 1072) * 256 + tid;
    const int id = ids[m];
    const float4* e4 = reinterpret_cast<const float4*>(ET + (size_t)id * EE);

    float a[NAx];
#pragma unroll
    for (int t = 0; t < NAx; ++t) a[t] = axb[t];

    for (int q = 0; q < EE / 4; ++q) {
      float4 v = e4[q];
#pragma unroll
      for (int c = 0; c < 4; ++c) {
        float x = (c == 0) ? v.x : (c == 1) ? v.y : (c == 2) ? v.z : v.w;
        const float* wrow = &sw[(q * 4 + c) * NAx];
#pragma unroll
        for (int t = 0; t < NAx; ++t) a[t] += x * wrow[t];
      }
    }
    {
      float mean = 0.f;
#pragma unroll
      for (int t = 0; t < NAx; ++t) mean += a[t];
      mean *= (1.0f / NAx);
      float var = 0.f;
#pragma unroll
      for (int t = 0; t < NAx; ++t) { float d = a[t] - mean; var += d * d; }
      var *= (1.0f / NAx);
      float rs = rsqrtf(var + 1e-5f);
#pragma unroll
      for (int t = 0; t < NAx; ++t)
        a[t] = tanhf((a[t] - mean) * rs * axg[t] + axbeta[t]);
    }
    float c24[NCc];
#pragma unroll
    for (int j = 0; j < NCc; ++j) c24[j] = cb[j];
#pragma unroll
    for (int t = 0; t < NAx; ++t) {
      float x = a[t];
      const float* wrow = &scw[t * NCc];
#pragma unroll
      for (int j = 0; j < NCc; ++j) c24[j] += x * wrow[j];
    }
    {
      float mean = 0.f;
#pragma unroll
      for (int j = 0; j < NCc; ++j) mean += c24[j];
      mean *= (1.0f / NCc);
      float var = 0.f;
#pragma unroll
      for (int j = 0; j < NCc; ++j) { float d = c24[j] - mean; var += d * d; }
      var *= (1.0f / NCc);
      float rs = rsqrtf(var + 1e-5f);
#pragma unroll
      for (int j = 0; j < NCc; ++j)
        c24[j] = tanhf((c24[j] - mean) * rs * cg[j] + cbeta[j]);
    }
#pragma unroll
    for (int j = 0; j < NCc; ++j) comps[(size_t)m * NCc + j] = c24[j];
  }
}

// ---------------- state recurrence: 4 chunks/batch, 128-step warmup --------
// chunk c stores t in [c*128, c*128+128); warm-started at c*128-128 from zero.
// truncation error = 0.9^128 * |st| ~ 4e-6 (threshold 0.074). 32 blocks.
__global__ __launch_bounds__(576) void k_recurrence(
    const float* __restrict__ comps, const float* __restrict__ mix,
    __hip_bfloat16* __restrict__ ST, float* __restrict__ fstate)
{
  __shared__ float sc[256 * NCc];   // 24.6 KB
  const int bid = blockIdx.x;
  const int b = bid >> 2, c = bid & 3;
  const int tid = threadIdx.x;
  const int ts = c * 128;                     // first stored step
  const int t0 = (c == 0) ? 0 : ts - 128;     // warmup start
  const int rows = ts + 128 - t0;             // 128 or 256

  const float* src = comps + ((size_t)b * SS + t0) * NCc;
  for (int i = tid; i < rows * NCc; i += 576) sc[i] = src[i];
  __syncthreads();

  const float sm_ = 1.0f / (1.0f + expf(-mix[0]));
  const int i = tid / NCc, j = tid - i * NCc;
  float st = 0.0f;

  const int warm = rows - 128;
  for (int t = 0; t < warm; ++t)
    st = 0.9f * st + sm_ * sc[t * NCc + i] * sc[t * NCc + j];

  __hip_bfloat16* stp = ST + ((size_t)b * SS + ts) * NSt + tid;
  float ci = sc[warm * NCc + i], cj = sc[warm * NCc + j];
#pragma unroll 4
  for (int t = 0; t < 128; ++t) {
    const int tn = warm + t + 1;
    float nci = (t < 127) ? sc[tn * NCc + i] : 0.f;
    float ncj = (t < 127) ? sc[tn * NCc + j] : 0.f;
    st = 0.9f * st + sm_ * ci * cj;
    stp[(size_t)t * NSt] = __float2bfloat16(st);
    ci = nci; cj = ncj;
  }
  if (c == 3) fstate[b * NSt + tid] = st;
}

// ---------------- 128^2 bf16 GEMM (m97 structure) for GEMM1 ----------------
__global__ __launch_bounds__(256) void k_gemm_bt_gelu(
    const __hip_bfloat16* __restrict__ A,   // [M,K]
    const __hip_bfloat16* __restrict__ Bt,  // [N,K]
    const float* __restrict__ bias,
    __hip_bfloat16* __restrict__ Cb,
    int M, int N, int K)
{
  __shared__ __align__(16) __hip_bfloat16 As[128 * 32];
  __shared__ __align__(16) __hip_bfloat16 Bs[128 * 32];
  const int tid  = threadIdx.x;
  const int lane = tid & 63;
  const int w    = tid >> 6;
  const int wr   = w >> 1, wc = w & 1;
  const int m0 = blockIdx.y * 128;
  const int n0 = blockIdx.x * 128;
  const int lr = lane & 15;
  const int kb = lane >> 4;

  f32x4 acc[4][4];
#pragma unroll
  for (int i = 0; i < 4; ++i)
#pragma unroll
    for (int j = 0; j < 4; ++j) acc[i][j] = (f32x4){0.f, 0.f, 0.f, 0.f};

  for (int k0 = 0; k0 < K; k0 += 32) {
    __syncthreads();
#pragma unroll
    for (int p = 0; p < 2; ++p) {
      const int lbase = w * 2048 + p * 1024;
      const int o  = lbase + lane * 16;
      const int r  = o >> 6;
      const int sg = (o >> 4) & 3;
      gl2lds16(A  + (size_t)(m0 + r) * K + k0 + sg * 8, (char*)As + lbase);
      gl2lds16(Bt + (size_t)(n0 + r) * K + k0 + sg * 8, (char*)Bs + lbase);
    }
    asm volatile("s_waitcnt vmcnt(0)" ::: "memory");
    __syncthreads();

    bf16x8 af[4], bv[4];
#pragma unroll
    for (int mr = 0; mr < 4; ++mr)
      af[mr] = *reinterpret_cast<const bf16x8*>(&As[(wr * 64 + mr * 16 + lr) * 32 + kb * 8]);
#pragma unroll
    for (int nr = 0; nr < 4; ++nr)
      bv[nr] = *reinterpret_cast<const bf16x8*>(&Bs[(wc * 64 + nr * 16 + lr) * 32 + kb * 8]);
#pragma unroll
    for (int mr = 0; mr < 4; ++mr)
#pragma unroll
      for (int nr = 0; nr < 4; ++nr)
        acc[mr][nr] = MFMA16(af[mr], bv[nr], acc[mr][nr]);
  }

#pragma unroll
  for (int nr = 0; nr < 4; ++nr) {
    const int col = n0 + wc * 64 + nr * 16 + lr;
    const float bvs = bias[col];
#pragma unroll
    for (int mr = 0; mr < 4; ++mr) {
      const int rbase = m0 + wr * 64 + mr * 16 + kb * 4;
#pragma unroll
      for (int r = 0; r < 4; ++r) {
        float v = acc[mr][nr][r] + bvs;
        v = 0.5f * v * (1.0f + erff(v * 0.70710678118654752f));
        Cb[(size_t)(rbase + r) * N + col] = __float2bfloat16(v);
      }
    }
  }
}

// ---------------- GEMM2: 128^2 tile, BK=64, 4 waves, 2 blocks/CU ----------
// EXACT round-7 structure (best known): counted-vmcnt 4-phase K-loop,
// mt-fastest XCD swizzle, LDS-coalesced epilogue, NT f32x4 stores.
// Requires: M%128==0, N%128==0, K%64==0, K/64>=2, grid%8==0.
__global__ __launch_bounds__(256, 2) void k_gemm2_128(
    const __hip_bfloat16* __restrict__ A,   // [M,K]
    const __hip_bfloat16* __restrict__ Bt,  // [N,K]
    const float* __restrict__ bias,
    float* __restrict__ C,
    int M, int N, int K, int tiles_m)
{
  __shared__ __align__(16) char smem[65536];  // A: 2x16KB @0, B: 2x16KB @32768

  const int NK  = K >> 6;
  const int tid = threadIdx.x;
  const int lane = tid & 63;
  const int w  = tid >> 6;          // 0..3
  const int wr = w >> 1;            // M half
  const int wc = w & 1;             // N half
  const int lr = lane & 15;
  const int kb = lane >> 4;

  // T1: bijective XCD swizzle (grid % 8 == 0); mt fastest -> B panel L2-reuse
  const int nwg = gridDim.x;
  const int cpx = nwg >> 3;
  const int s   = ((int)blockIdx.x & 7) * cpx + ((int)blockIdx.x >> 3);
  const int nt  = s / tiles_m;
  const int mt  = s - nt * tiles_m;
  const int m0  = mt << 7;
  const int n0  = nt << 7;

  // stage-side (linear LDS dest, inverse-swizzled global source)
  const int srow = tid >> 3;                       // 0..31
  const int scol = ((tid & 7) ^ (srow & 7)) << 3;  // element offset in K-tile
  // read-side swizzle
  const int swz0 = (kb ^ (lr & 7)) << 4;
  const int swz1 = swz0 ^ 64;

  // one call stages a 32-row chunk (R in {0,32,64,96}) of a 128x64 bf16 tile
#define STAGE_A(buf, R, tk0)                                              \
  gl2lds16(A + (size_t)(m0 + (R) + srow) * K + (tk0) + scol,              \
           smem + (buf)*16384 + (R)*128 + w*1024)
#define STAGE_B(buf, R, tk0)                                              \
  gl2lds16(Bt + (size_t)(n0 + (R) + srow) * K + (tk0) + scol,             \
           smem + 32768 + (buf)*16384 + (R)*128 + w*1024)

#define LDA(buf, mf, kh) \
  (*(const bf16x8*)(smem + (buf)*16384 + (wr*64 + (mf)*16 + lr)*128 + ((kh) ? swz1 : swz0)))
#define LDB(buf, nf, kh) \
  (*(const bf16x8*)(smem + 32768 + (buf)*16384 + (wc*64 + (nf)*16 + lr)*128 + ((kh) ? swz1 : swz0)))

  f32x4 acc[4][4];
#pragma unroll
  for (int i = 0; i < 4; ++i)
#pragma unroll
    for (int j = 0; j < 4; ++j) acc[i][j] = (f32x4){0.f, 0.f, 0.f, 0.f};

  float bvs[4];
#pragma unroll
  for (int nf = 0; nf < 4; ++nf) bvs[nf] = bias[n0 + wc * 64 + nf * 16 + lr];

  // ---- prologue: A(0), B(0), B(1)  (12 loads/thread, wait oldest 8)
  STAGE_A(0, 0, 0);  STAGE_A(0, 32, 0);  STAGE_A(0, 64, 0);  STAGE_A(0, 96, 0);
  STAGE_B(0, 0, 0);  STAGE_B(0, 32, 0);  STAGE_B(0, 64, 0);  STAGE_B(0, 96, 0);
  STAGE_B(1, 0, 64); STAGE_B(1, 32, 64); STAGE_B(1, 64, 64); STAGE_B(1, 96, 64);
  asm volatile("s_waitcnt vmcnt(4)" ::: "memory");   // tile0 (A+B) landed
  BAR();

#pragma unroll 1
  for (int t = 0; t < NK; ++t) {
    const int c  = t & 1;
    const int k1 = (t + 1) << 6;
    const int k2 = (t + 2) << 6;
    bf16x8 a0[4], b0[4], a1[4], b1[4];

    // phase 0: read kh0 frags; stage A(t+1) half; MFMA kh0 x nf0,1
#pragma unroll
    for (int mf = 0; mf < 4; ++mf) a0[mf] = LDA(c, mf, 0);
#pragma unroll
    for (int nf = 0; nf < 4; ++nf) b0[nf] = LDB(c, nf, 0);
    if (t < NK - 1) { STAGE_A(c ^ 1, 0, k1); STAGE_A(c ^ 1, 32, k1); }
    BAR();
    asm volatile("s_waitcnt lgkmcnt(0)" ::: "memory");
    __builtin_amdgcn_sched_barrier(0);
    __builtin_amdgcn_s_setprio(1);
#pragma unroll
    for (int mf = 0; mf < 4; ++mf) {
      acc[mf][0] = MFMA16(a0[mf], b0[0], acc[mf][0]);
      acc[mf][1] = MFMA16(a0[mf], b0[1], acc[mf][1]);
    }
    __builtin_amdgcn_s_setprio(0);
    BAR();

    // phase 1: read kh1 frags; stage A(t+1) half; MFMA kh0 x nf2,3
#pragma unroll
    for (int mf = 0; mf < 4; ++mf) a1[mf] = LDA(c, mf, 1);
#pragma unroll
    for (int nf = 0; nf < 4; ++nf) b1[nf] = LDB(c, nf, 1);
    if (t < NK - 1) { STAGE_A(c ^ 1, 64, k1); STAGE_A(c ^ 1, 96, k1); }
    BAR();
    asm volatile("s_waitcnt lgkmcnt(0)" ::: "memory");   // buf c fully consumed
    __builtin_amdgcn_sched_barrier(0);
    __builtin_amdgcn_s_setprio(1);
#pragma unroll
    for (int mf = 0; mf < 4; ++mf) {
      acc[mf][2] = MFMA16(a0[mf], b0[2], acc[mf][2]);
      acc[mf][3] = MFMA16(a0[mf], b0[3], acc[mf][3]);
    }
    __builtin_amdgcn_s_setprio(0);
    BAR();

    // phase 2: stage B(t+2) into just-freed buf c; MFMA kh1 x nf0,1
    if (t < NK - 2) { STAGE_B(c, 0, k2); STAGE_B(c, 32, k2); }
    BAR();
    __builtin_amdgcn_s_setprio(1);
#pragma unroll
    for (int mf = 0; mf < 4; ++mf) {
      acc[mf][0] = MFMA16(a1[mf], b1[0], acc[mf][0]);
      acc[mf][1] = MFMA16(a1[mf], b1[1], acc[mf][1]);
    }
    __builtin_amdgcn_s_setprio(0);
    BAR();

    // phase 3: stage B(t+2); MFMA kh1 x nf2,3; boundary wait
    if (t < NK - 2) { STAGE_B(c, 64, k2); STAGE_B(c, 96, k2); }
    BAR();
    __builtin_amdgcn_s_setprio(1);
#pragma unroll
    for (int mf = 0; mf < 4; ++mf) {
      acc[mf][2] = MFMA16(a1[mf], b1[2], acc[mf][2]);
      acc[mf][3] = MFMA16(a1[mf], b1[3], acc[mf][3]);
    }
    __builtin_amdgcn_s_setprio(0);
    if (t < NK - 2) {
      asm volatile("s_waitcnt vmcnt(4)" ::: "memory");   // tile t+1 landed
    } else if (t == NK - 2) {
      asm volatile("s_waitcnt vmcnt(0)" ::: "memory");
    }
    BAR();
  }

  // ---- epilogue: one LDS phase (128x128 f32 = 64 KB), 512B-contig NT stores
  float* ls = (float*)smem;
#pragma unroll
  for (int mf = 0; mf < 4; ++mf) {
#pragma unroll
    for (int nf = 0; nf < 4; ++nf) {
      const int col = wc * 64 + nf * 16 + lr;
#pragma unroll
      for (int r = 0; r < 4; ++r) {
        const int row = wr * 64 + mf * 16 + kb * 4 + r;
        const int seg = (col >> 2) ^ (row & 7);
        ls[row * 128 + seg * 4 + (col & 3)] = acc[mf][nf][r] + bvs[nf];
      }
    }
  }
  asm volatile("s_waitcnt lgkmcnt(0)" ::: "memory");
  BAR();
#pragma unroll
  for (int pass = 0; pass < 16; ++pass) {
    const int lrow = pass * 8 + w * 2 + (lane >> 5);
    const int seg  = (lane & 31) ^ (lrow & 7);
    f32x4 v = *(const f32x4*)&ls[lrow * 128 + seg * 4];
    __builtin_nontemporal_store(v,
        (f32x4*)&C[(size_t)(m0 + lrow) * N + n0 + (lane & 31) * 4]);
  }
#undef STAGE_A
#undef STAGE_B
#undef LDA
#undef LDB
}

// ---------------- launch ----------------
extern "C" void kernel_launch(void* const* d_in, const int* in_sizes, int n_in,
                              void* d_out, int out_size, void* d_ws, size_t ws_size,
                              hipStream_t stream) {
  const int*   ids  = (const int*)  d_in[0];
  const float* ET   = (const float*)d_in[1];
  const float* axw  = (const float*)d_in[2];
  const float* axb  = (const float*)d_in[3];
  const float* axg  = (const float*)d_in[4];
  const float* axbt = (const float*)d_in[5];
  const float* cw   = (const float*)d_in[6];
  const float* cb   = (const float*)d_in[7];
  const float* cg   = (const float*)d_in[8];
  const float* cbt  = (const float*)d_in[9];
  const float* mix  = (const float*)d_in[10];
  const float* w1   = (const float*)d_in[11];
  const float* b1   = (const float*)d_in[12];
  const float* w2   = (const float*)d_in[13];
  const float* b2   = (const float*)d_in[14];

  float* out = (float*)d_out;

  char* ws = (char*)d_ws;
  size_t o = 0;
  __hip_bfloat16* W2T   = (__hip_bfloat16*)(ws + o); o += (size_t)VV * 512 * 2;
  __hip_bfloat16* W1T   = (__hip_bfloat16*)(ws + o); o += (size_t)512 * NSt * 2;
  float*          comps = (float*)(ws + o);          o += (size_t)MM * NCc * 4;
  __hip_bfloat16* STb   = (__hip_bfloat16*)(ws + o); o += (size_t)MM * NSt * 2;
  __hip_bfloat16* H     = (__hip_bfloat16*)(ws + o); o += (size_t)MM * 512 * 2;

  // fused prep: W2T + W1T + comps in one launch (1088 blocks)
  k_prep<<<1088, 256, 0, stream>>>(w2, W2T, w1, W1T, ids, ET,
                                   axw, axb, axg, axbt,
                                   cw, cb, cg, cbt, comps);

  // chunk-parallel recurrence (32 blocks), fstate into d_out tail
  k_recurrence<<<32, NSt, 0, stream>>>(comps, mix, STb, out + (size_t)MM * VV);

  // GEMM1: H = gelu(ST @ W1 + b1)  (M=4096, N=512, K=576)
  k_gemm_bt_gelu<<<dim3(512 / 128, MM / 128), 256, 0, stream>>>(
      STb, W1T, b1, H, MM, 512, NSt);

  // GEMM2: logits = H @ W2 + b2  (M=4096, N=32000, K=512), r7 config
  k_gemm2_128<<<(VV / 128) * (MM / 128), 256, 0, stream>>>(
      H, W2T, b2, out, MM, VV, 512, MM / 128);
}